// Round 9
// baseline (529.439 us; speedup 1.0000x reference)
//
#include <hip/hip_runtime.h>
#include <math.h>

#define VOXN 32768

// ---- workspace layout (float offsets) ----
constexpr int OFF_STATS_Y   = 0;        // 512
constexpr int OFF_STATS_X2P = 512;      // 256
constexpr int OFF_STATS_H   = 768;      // 512
constexpr int OFF_TPAR      = 1280;     // 1024*16 packed tap params (SORTED order)
constexpr int OFF_W1T       = 17664;    // 65536: [g][cSorted(256)][o(64)]
constexpr int OFF_W2T       = 83200;    // 32768
constexpr int OFF_W3AT      = 115968;   // 4096
constexpr int OFF_W3BT      = 120064;   // 5120
constexpr int OFF_W3CT      = 125184;   // 6144
constexpr int OFF_W3DT      = 131328;   // 7168
constexpr int OFF_W4T       = 138496;   // 2048
constexpr int OFF_YH        = 140544;   // 8388608 (y, later H)
constexpr int OFF_C0A       = OFF_YH;       // 1024 ints (dead before s1 writes y)
constexpr int OFF_PERM      = OFF_YH + 1024;// 1024 ints
constexpr int OFF_X2P       = 8529152;  // 4194304 (x2pre; ALSO hosts pvolP early)
constexpr int OFF_PVOLP     = OFF_X2P;  // 941192 float2, dead before s2

#define FMA4(A, W, X) { (A).x = fmaf((W).x, (X), (A).x); (A).y = fmaf((W).y, (X), (A).y); \
                        (A).z = fmaf((W).z, (X), (A).z); (A).w = fmaf((W).w, (X), (A).w); }
#define ADD4(A, T) { (A).x += (T).x; (A).y += (T).y; (A).z += (T).z; (A).w += (T).w; }
#define RELU4(A) { (A).x = fmaxf((A).x, 0.f); (A).y = fmaxf((A).y, 0.f); \
                   (A).z = fmaxf((A).z, 0.f); (A).w = fmaxf((A).w, 0.f); }
#define ZERO4(A) float4 A; (A).x = 0.f; (A).y = 0.f; (A).z = 0.f; (A).w = 0.f;

#define BFLY(s, q) { s += __shfl_xor(s, 32, 64); q += __shfl_xor(q, 32, 64); \
                     s += __shfl_xor(s, 16, 64); q += __shfl_xor(q, 16, 64); \
                     s += __shfl_xor(s,  8, 64); q += __shfl_xor(q,  8, 64); \
                     s += __shfl_xor(s,  4, 64); q += __shfl_xor(q,  4, 64); \
                     s += __shfl_xor(s,  2, 64); q += __shfl_xor(q,  2, 64); \
                     s += __shfl_xor(s,  1, 64); q += __shfl_xor(q,  1, 64); }
#define STASH1(V, O) { float s_ = (V), q_ = (V) * (V); BFLY(s_, q_) \
                       if (lane == (O)) { ms = s_; mq = q_; } }
#define STASH4(A, O0) STASH1((A).x, (O0)+0) STASH1((A).y, (O0)+1) \
                      STASH1((A).z, (O0)+2) STASH1((A).w, (O0)+3)

__device__ __forceinline__ float pv_at(const float* __restrict__ images, int j) {
  int x = j % 98, t = j / 98, y = t % 98, z = t / 98;
  if (x >= 33 && x < 65 && y >= 33 && y < 65 && z >= 33 && z < 65)
    return images[((z - 33) * 32 + (y - 33)) * 32 + (x - 33)];
  return 0.f;
}

__device__ __forceinline__ int tap_c0(const float* __restrict__ offset1, int k, int s) {
  float ox = fminf(fmaxf(offset1[k * 6 + s * 3 + 0] * 16.f, -1000.f), 1000.f);
  float oy = fminf(fmaxf(offset1[k * 6 + s * 3 + 1] * 16.f, -1000.f), 1000.f);
  float oz = fminf(fmaxf(offset1[k * 6 + s * 3 + 2] * 16.f, -1000.f), 1000.f);
  int sx = (int)floorf(ox), sy = (int)floorf(oy), sz = (int)floorf(oz);
  bool valid = (sx >= -33 && sx <= 32) && (sy >= -33 && sy <= 32) && (sz >= -33 && sz <= 32);
  if (!valid) { sx = sy = sz = 0; }
  return (sz + 33) * 9604 + (sy + 33) * 98 + (sx + 33);
}

// ---------------- S0a ----------------
__global__ void s0a_setup(const float* __restrict__ images, const float* __restrict__ offset1,
                          const float* __restrict__ w2,
                          const float* __restrict__ w3a, const float* __restrict__ w3b,
                          const float* __restrict__ w3c, const float* __restrict__ w3d,
                          const float* __restrict__ w4, float* __restrict__ ws)
{
  const int idx = blockIdx.x * blockDim.x + threadIdx.x;
  const int stride = gridDim.x * blockDim.x;
  for (int i = idx; i < 1280; i += stride) ws[i] = 0.f;
  float2* pp = (float2*)(ws + OFF_PVOLP);
  for (int i = idx; i < 941192; i += stride) {
    float v0 = pv_at(images, i);
    float v1 = (i + 1 < 941192) ? pv_at(images, i + 1) : 0.f;
    float2 f; f.x = v0; f.y = v1;
    pp[i] = f;
  }
  int* c0a = (int*)(ws + OFF_C0A);
  for (int k = idx; k < 1024; k += stride) c0a[k] = tap_c0(offset1, k, 0);
  for (int i = idx; i < 32768; i += stride) { int o = i & 127, c = i >> 7; ws[OFF_W2T + i] = w2[o * 256 + c]; }
  for (int i = idx; i < 4096;  i += stride) { int o = i & 31,  c = i >> 5; ws[OFF_W3AT + i] = w3a[o * 128 + c]; }
  for (int i = idx; i < 5120;  i += stride) { int o = i & 31,  c = i >> 5; ws[OFF_W3BT + i] = w3b[o * 160 + c]; }
  for (int i = idx; i < 6144;  i += stride) { int o = i & 31,  c = i >> 5; ws[OFF_W3CT + i] = w3c[o * 192 + c]; }
  for (int i = idx; i < 7168;  i += stride) { int o = i & 31,  c = i >> 5; ws[OFF_W3DT + i] = w3d[o * 224 + c]; }
  for (int i = idx; i < 2048;  i += stride) { int l = i & 7,   c = i >> 3; ws[OFF_W4T + i] = w4[l * 256 + c]; }
}

// ---------------- S0b ----------------
__global__ void s0b_rank(float* __restrict__ ws)
{
  const int idx = blockIdx.x * blockDim.x + threadIdx.x;
  if (idx >= 1024) return;
  const int g = idx >> 8, k = idx & 255;
  const int* c0a = (const int*)(ws + OFF_C0A);
  int* perm = (int*)(ws + OFF_PERM);
  const int my = c0a[g * 256 + k];
  int rank = 0;
  for (int j = 0; j < 256; ++j) {
    int cj = c0a[g * 256 + j];
    rank += (cj < my) || (cj == my && j < k);
  }
  perm[g * 256 + rank] = k;
}

// ---------------- S0c ----------------
__global__ void s0c_build(const float* __restrict__ offset1, const float* __restrict__ w1,
                          float* __restrict__ ws)
{
  const int idx = blockIdx.x * blockDim.x + threadIdx.x;
  const int stride = gridDim.x * blockDim.x;
  const int* perm = (const int*)(ws + OFF_PERM);
  for (int p = idx; p < 1024; p += stride) {
    const int g = p >> 8;
    const int k = g * 256 + perm[p];
    float* tp = ws + OFF_TPAR + p * 16;
    for (int s = 0; s < 2; ++s) {
      float ox = fminf(fmaxf(offset1[k * 6 + s * 3 + 0] * 16.f, -1000.f), 1000.f);
      float oy = fminf(fmaxf(offset1[k * 6 + s * 3 + 1] * 16.f, -1000.f), 1000.f);
      float oz = fminf(fmaxf(offset1[k * 6 + s * 3 + 2] * 16.f, -1000.f), 1000.f);
      float fxf = floorf(ox), fyf = floorf(oy), fzf = floorf(oz);
      float fx = ox - fxf, fy = oy - fyf, fz = oz - fzf;
      int sx = (int)fxf, sy = (int)fyf, sz = (int)fzf;
      bool valid = (sx >= -33 && sx <= 32) && (sy >= -33 && sy <= 32) && (sz >= -33 && sz <= 32);
      if (!valid) { sx = sy = sz = 0; }
      float vm = valid ? 1.f : 0.f;
      int c0 = (sz + 33) * 9604 + (sy + 33) * 98 + (sx + 33);
      float sgn = s ? -1.f : 1.f;
      float wy0 = 1.f - fy, wy1 = fy, wz0 = 1.f - fz, wz1 = fz;
      tp[s * 8 + 0] = __int_as_float(c0);
      tp[s * 8 + 1] = vm * (1.f - fx);
      tp[s * 8 + 2] = vm * fx;
      tp[s * 8 + 3] = vm * sgn * wz0 * wy0;
      tp[s * 8 + 4] = vm * sgn * wz0 * wy1;
      tp[s * 8 + 5] = vm * sgn * wz1 * wy0;
      tp[s * 8 + 6] = vm * sgn * wz1 * wy1;
      tp[s * 8 + 7] = 0.f;
    }
  }
  for (int i = idx; i < 65536; i += stride) {
    int o = i & 63, t = i >> 6, c = t & 255, g = t >> 8;
    int ksrc = perm[g * 256 + c];
    ws[OFF_W1T + i] = w1[g * 16384 + o * 256 + ksrc];
  }
}

// ---------------- S1: fused gather + grouped GEMM, 4 k-quarter subgroups ----------------
// Block 512 thr = 4 subgroups (k-quarters) x 2 waves (128 voxels).
// grid (256,4) = 1024 blocks = 4 blocks/CU -> 32 waves/CU target.
__global__ __launch_bounds__(512, 4) void s1_gather_gemm(
    const float2* __restrict__ pvolP, const float* __restrict__ tparP,
    const float* __restrict__ w1t, float* __restrict__ y, float* __restrict__ stats_y)
{
  __shared__ float wlds[4][32 * 64];      // 32 KB
  __shared__ float redS[2][64], redQ[2][64];
  const int tid = threadIdx.x;
  const int lane = tid & 63;
  const int wv = tid >> 6;       // 0..7
  const int sub = wv >> 1;       // k-quarter 0..3
  const int vw = wv & 1;         // voxel-wave
  const int g = blockIdx.y;
  const int v = blockIdx.x * 128 + vw * 64 + lane;
  const int vbase = (v >> 10) * 9604 + ((v >> 5) & 31) * 98 + (v & 31);
  const int sidx = vw * 64 + lane;          // 0..127 within subgroup
  const int kq0 = sub * 64;

  ZERO4(a0) ZERO4(a1) ZERO4(a2) ZERO4(a3) ZERO4(a4) ZERO4(a5) ZERO4(a6) ZERO4(a7)
  ZERO4(a8) ZERO4(a9) ZERO4(a10) ZERO4(a11) ZERO4(a12) ZERO4(a13) ZERO4(a14) ZERO4(a15)

  const float4* tq_base = (const float4*)(tparP + g * 4096);

  for (int ch = 0; ch < 2; ++ch) {
    __syncthreads();
    { // stage this subgroup's 32-k weight chunk: 512 float4s by 128 threads
      const float4* src = (const float4*)(w1t + ((size_t)(g * 256 + kq0 + ch * 32)) * 64);
      float4* dst = (float4*)&wlds[sub][0];
      #pragma unroll
      for (int j = 0; j < 4; ++j) dst[sidx + j * 128] = src[sidx + j * 128];
    }
    __syncthreads();
    #pragma unroll 2
    for (int kk = 0; kk < 32; ++kk) {
      const int kt = kq0 + ch * 32 + kk;
      float4 t0 = tq_base[kt * 4 + 0];
      float4 t1 = tq_base[kt * 4 + 1];
      float4 t2 = tq_base[kt * 4 + 2];
      float4 t3 = tq_base[kt * 4 + 3];
      float xval;
      {
        const float2* p = pvolP + (vbase + __float_as_int(t0.x));
        float2 r0 = p[0], r1 = p[98], r2 = p[9604], r3 = p[9702];
        float h0 = r0.x * t0.y + r0.y * t0.z;
        float h1 = r1.x * t0.y + r1.y * t0.z;
        float h2 = r2.x * t0.y + r2.y * t0.z;
        float h3 = r3.x * t0.y + r3.y * t0.z;
        xval = h0 * t0.w + h1 * t1.x + h2 * t1.y + h3 * t1.z;
      }
      {
        const float2* p = pvolP + (vbase + __float_as_int(t2.x));
        float2 r0 = p[0], r1 = p[98], r2 = p[9604], r3 = p[9702];
        float h0 = r0.x * t2.y + r0.y * t2.z;
        float h1 = r1.x * t2.y + r1.y * t2.z;
        float h2 = r2.x * t2.y + r2.y * t2.z;
        float h3 = r3.x * t2.y + r3.y * t2.z;
        xval += h0 * t2.w + h1 * t3.x + h2 * t3.y + h3 * t3.z; // tap b pre-negated
      }
      const float4* wk = (const float4*)&wlds[sub][kk * 64];
      float4 w;
      w = wk[0];  FMA4(a0,  w, xval)
      w = wk[1];  FMA4(a1,  w, xval)
      w = wk[2];  FMA4(a2,  w, xval)
      w = wk[3];  FMA4(a3,  w, xval)
      w = wk[4];  FMA4(a4,  w, xval)
      w = wk[5];  FMA4(a5,  w, xval)
      w = wk[6];  FMA4(a6,  w, xval)
      w = wk[7];  FMA4(a7,  w, xval)
      w = wk[8];  FMA4(a8,  w, xval)
      w = wk[9];  FMA4(a9,  w, xval)
      w = wk[10]; FMA4(a10, w, xval)
      w = wk[11]; FMA4(a11, w, xval)
      w = wk[12]; FMA4(a12, w, xval)
      w = wk[13]; FMA4(a13, w, xval)
      w = wk[14]; FMA4(a14, w, xval)
      w = wk[15]; FMA4(a15, w, xval)
    }
  }
  // ---- combine: tree (sub1->sub0, sub3->sub2) then (sub2->sub0) ----
  __syncthreads();
  float4* cbuf = (float4*)&wlds[0][0];
  #define CRA(A0, A1, A2, A3) \
    if (sub == 1) { int bi = sidx * 4; \
      cbuf[bi] = A0; cbuf[bi + 1] = A1; cbuf[bi + 2] = A2; cbuf[bi + 3] = A3; } \
    else if (sub == 3) { int bi = 512 + sidx * 4; \
      cbuf[bi] = A0; cbuf[bi + 1] = A1; cbuf[bi + 2] = A2; cbuf[bi + 3] = A3; } \
    __syncthreads(); \
    if (sub == 0) { int bi = sidx * 4; float4 t_; \
      t_ = cbuf[bi];     ADD4(A0, t_) \
      t_ = cbuf[bi + 1]; ADD4(A1, t_) \
      t_ = cbuf[bi + 2]; ADD4(A2, t_) \
      t_ = cbuf[bi + 3]; ADD4(A3, t_) } \
    else if (sub == 2) { int bi = 512 + sidx * 4; float4 t_; \
      t_ = cbuf[bi];     ADD4(A0, t_) \
      t_ = cbuf[bi + 1]; ADD4(A1, t_) \
      t_ = cbuf[bi + 2]; ADD4(A2, t_) \
      t_ = cbuf[bi + 3]; ADD4(A3, t_) } \
    __syncthreads();
  CRA(a0, a1, a2, a3)
  CRA(a4, a5, a6, a7)
  CRA(a8, a9, a10, a11)
  CRA(a12, a13, a14, a15)
  #undef CRA
  #define CRB(A0, A1, A2, A3) \
    if (sub == 2) { int bi = sidx * 4; \
      cbuf[bi] = A0; cbuf[bi + 1] = A1; cbuf[bi + 2] = A2; cbuf[bi + 3] = A3; } \
    __syncthreads(); \
    if (sub == 0) { int bi = sidx * 4; float4 t_; \
      t_ = cbuf[bi];     ADD4(A0, t_) \
      t_ = cbuf[bi + 1]; ADD4(A1, t_) \
      t_ = cbuf[bi + 2]; ADD4(A2, t_) \
      t_ = cbuf[bi + 3]; ADD4(A3, t_) } \
    __syncthreads();
  CRB(a0, a1, a2, a3)
  CRB(a4, a5, a6, a7)
  CRB(a8, a9, a10, a11)
  CRB(a12, a13, a14, a15)
  #undef CRB

  const int obase = g << 6;
  if (sub == 0) {
    #define S1_ST(A, o0) \
      y[((size_t)(obase + (o0) + 0)) * VOXN + v] = (A).x; \
      y[((size_t)(obase + (o0) + 1)) * VOXN + v] = (A).y; \
      y[((size_t)(obase + (o0) + 2)) * VOXN + v] = (A).z; \
      y[((size_t)(obase + (o0) + 3)) * VOXN + v] = (A).w;
    S1_ST(a0, 0)   S1_ST(a1, 4)   S1_ST(a2, 8)   S1_ST(a3, 12)
    S1_ST(a4, 16)  S1_ST(a5, 20)  S1_ST(a6, 24)  S1_ST(a7, 28)
    S1_ST(a8, 32)  S1_ST(a9, 36)  S1_ST(a10, 40) S1_ST(a11, 44)
    S1_ST(a12, 48) S1_ST(a13, 52) S1_ST(a14, 56) S1_ST(a15, 60)
    #undef S1_ST
    float ms = 0.f, mq = 0.f;
    STASH4(a0, 0)   STASH4(a1, 4)   STASH4(a2, 8)   STASH4(a3, 12)
    STASH4(a4, 16)  STASH4(a5, 20)  STASH4(a6, 24)  STASH4(a7, 28)
    STASH4(a8, 32)  STASH4(a9, 36)  STASH4(a10, 40) STASH4(a11, 44)
    STASH4(a12, 48) STASH4(a13, 52) STASH4(a14, 56) STASH4(a15, 60)
    redS[vw][lane] = ms; redQ[vw][lane] = mq;
  }
  __syncthreads();
  if (tid < 64) {
    float s = redS[0][tid] + redS[1][tid];
    float q = redQ[0][tid] + redQ[1][tid];
    atomicAdd(&stats_y[obase + tid], s);
    atomicAdd(&stats_y[256 + obase + tid], q);
  }
}

// ---------------- S2: x1=relu(BN(y)); x2pre = w2@x1. 512 thr = 4 o-quarters x 128 vox.
// y read ONCE per block via LDS-staged BN'd tile. grid(256).
__global__ __launch_bounds__(512) void s2_bn_gemm(
    const float* __restrict__ y, const float* __restrict__ stats_y,
    const float* __restrict__ g1, const float* __restrict__ b1,
    const float* __restrict__ w2t, float* __restrict__ x2p, float* __restrict__ stats_x2p)
{
  __shared__ float As[256], Bs[256];
  __shared__ float tile[32][128];
  __shared__ float redS[8][32], redQ[8][32];
  const int tid = threadIdx.x;
  const int lane = tid & 63;
  const int wv = tid >> 6;
  const int q = tid >> 7;            // o-quarter 0..3
  const int vox = tid & 127;
  const int nb = blockIdx.x * 128;
  const int n = nb + vox;
  if (tid < 256) {
    float m = stats_y[tid] * (1.f / VOXN);
    float vv = stats_y[256 + tid] * (1.f / VOXN) - m * m;
    float a = g1[tid] * rsqrtf(vv + 1e-5f);
    As[tid] = a; Bs[tid] = b1[tid] - m * a;
  }
  ZERO4(a0) ZERO4(a1) ZERO4(a2) ZERO4(a3) ZERO4(a4) ZERO4(a5) ZERO4(a6) ZERO4(a7)
  for (int cc = 0; cc < 256; cc += 32) {
    __syncthreads();
    #pragma unroll
    for (int e = 0; e < 8; ++e) {
      int i = tid + e * 512;
      int c = i >> 7, vx = i & 127;
      tile[c][vx] = fmaxf(fmaf(y[(size_t)(cc + c) * VOXN + nb + vx], As[cc + c], Bs[cc + c]), 0.f);
    }
    __syncthreads();
    #pragma unroll 4
    for (int c = 0; c < 32; ++c) {
      float t = tile[c][vox];
      const float4* wk = (const float4*)(w2t + (cc + c) * 128 + q * 32);
      float4 w;
      w = wk[0]; FMA4(a0, w, t)
      w = wk[1]; FMA4(a1, w, t)
      w = wk[2]; FMA4(a2, w, t)
      w = wk[3]; FMA4(a3, w, t)
      w = wk[4]; FMA4(a4, w, t)
      w = wk[5]; FMA4(a5, w, t)
      w = wk[6]; FMA4(a6, w, t)
      w = wk[7]; FMA4(a7, w, t)
    }
  }
  const int ob = q * 32;
  #define S2_ST(A, o0) \
    x2p[((size_t)(ob + (o0) + 0)) * VOXN + n] = (A).x; \
    x2p[((size_t)(ob + (o0) + 1)) * VOXN + n] = (A).y; \
    x2p[((size_t)(ob + (o0) + 2)) * VOXN + n] = (A).z; \
    x2p[((size_t)(ob + (o0) + 3)) * VOXN + n] = (A).w;
  S2_ST(a0, 0) S2_ST(a1, 4) S2_ST(a2, 8) S2_ST(a3, 12)
  S2_ST(a4, 16) S2_ST(a5, 20) S2_ST(a6, 24) S2_ST(a7, 28)
  #undef S2_ST
  float ms = 0.f, mq = 0.f;
  STASH4(a0, 0) STASH4(a1, 4) STASH4(a2, 8) STASH4(a3, 12)
  STASH4(a4, 16) STASH4(a5, 20) STASH4(a6, 24) STASH4(a7, 28)
  if (lane < 32) { redS[wv][lane] = ms; redQ[wv][lane] = mq; }
  __syncthreads();
  if (tid < 128) {
    int qq = tid >> 5, ch = tid & 31;
    float s = redS[2 * qq][ch] + redS[2 * qq + 1][ch];
    float sq = redQ[2 * qq][ch] + redQ[2 * qq + 1][ch];
    atomicAdd(&stats_x2p[tid], s);
    atomicAdd(&stats_x2p[128 + tid], sq);
  }
}

// ---------------- S3: x2=BN(x2pre)->H[0:128] (during staging); ha=relu(w3a@x2)->H[128:160]
__global__ __launch_bounds__(512) void s3_x2_ha(
    const float* __restrict__ x2p, const float* __restrict__ stats_x2p,
    const float* __restrict__ g2, const float* __restrict__ b2,
    const float* __restrict__ w3at, float* __restrict__ H, float* __restrict__ stats_H)
{
  __shared__ float As[128], Bs[128];
  __shared__ float tile[32][128];
  __shared__ float redS[8][8], redQ[8][8];
  const int tid = threadIdx.x;
  const int lane = tid & 63;
  const int wv = tid >> 6;
  const int q = tid >> 7;
  const int vox = tid & 127;
  const int nb = blockIdx.x * 128;
  const int n = nb + vox;
  if (tid < 128) {
    float m = stats_x2p[tid] * (1.f / VOXN);
    float vv = stats_x2p[128 + tid] * (1.f / VOXN) - m * m;
    float a = g2[tid] * rsqrtf(vv + 1e-5f);
    As[tid] = a; Bs[tid] = b2[tid] - m * a;
    if (blockIdx.x == 0) {
      float mean = b2[tid];
      float var = a * a * vv;
      stats_H[tid] = mean * (float)VOXN;
      stats_H[256 + tid] = (var + mean * mean) * (float)VOXN;
    }
  }
  ZERO4(a0) ZERO4(a1)
  for (int cc = 0; cc < 128; cc += 32) {
    __syncthreads();
    #pragma unroll
    for (int e = 0; e < 8; ++e) {
      int i = tid + e * 512;
      int c = i >> 7, vx = i & 127;
      float val = fmaf(x2p[(size_t)(cc + c) * VOXN + nb + vx], As[cc + c], Bs[cc + c]);
      tile[c][vx] = val;
      H[(size_t)(cc + c) * VOXN + nb + vx] = val;
    }
    __syncthreads();
    #pragma unroll 4
    for (int c = 0; c < 32; ++c) {
      float t = tile[c][vox];
      const float4* wk = (const float4*)(w3at + (cc + c) * 32 + q * 8);
      float4 w;
      w = wk[0]; FMA4(a0, w, t)
      w = wk[1]; FMA4(a1, w, t)
    }
  }
  RELU4(a0) RELU4(a1)
  const int ob = 128 + q * 8;
  #define S3_ST(A, o0) \
    H[((size_t)(ob + (o0) + 0)) * VOXN + n] = (A).x; \
    H[((size_t)(ob + (o0) + 1)) * VOXN + n] = (A).y; \
    H[((size_t)(ob + (o0) + 2)) * VOXN + n] = (A).z; \
    H[((size_t)(ob + (o0) + 3)) * VOXN + n] = (A).w;
  S3_ST(a0, 0) S3_ST(a1, 4)
  #undef S3_ST
  float ms = 0.f, mq = 0.f;
  STASH4(a0, 0) STASH4(a1, 4)
  if (lane < 8) { redS[wv][lane] = ms; redQ[wv][lane] = mq; }
  __syncthreads();
  if (tid < 32) {
    int qq = tid >> 3, ch = tid & 7;
    float s = redS[2 * qq][ch] + redS[2 * qq + 1][ch];
    float sq = redQ[2 * qq][ch] + redQ[2 * qq + 1][ch];
    atomicAdd(&stats_H[128 + tid], s);
    atomicAdd(&stats_H[256 + 128 + tid], sq);
  }
}

// ---------------- S4/5/6: h = relu(w @ BN(H[0:CIN])) -> H[och:och+32] ----------------
template<int CIN>
__global__ __launch_bounds__(512) void s_dense(
    const float* __restrict__ Hin, const float* __restrict__ stats_H,
    const float* __restrict__ g, const float* __restrict__ b,
    const float* __restrict__ wt, float* __restrict__ H, float* __restrict__ stats_out, int och)
{
  __shared__ float As[CIN], Bs[CIN];
  __shared__ float tile[32][128];
  __shared__ float redS[8][8], redQ[8][8];
  const int tid = threadIdx.x;
  const int lane = tid & 63;
  const int wv = tid >> 6;
  const int q = tid >> 7;
  const int vox = tid & 127;
  const int nb = blockIdx.x * 128;
  const int n = nb + vox;
  if (tid < CIN) {
    float m = stats_H[tid] * (1.f / VOXN);
    float vv = stats_H[256 + tid] * (1.f / VOXN) - m * m;
    float a = g[tid] * rsqrtf(vv + 1e-5f);
    As[tid] = a; Bs[tid] = b[tid] - m * a;
  }
  ZERO4(a0) ZERO4(a1)
  for (int cc = 0; cc < CIN; cc += 32) {
    __syncthreads();
    #pragma unroll
    for (int e = 0; e < 8; ++e) {
      int i = tid + e * 512;
      int c = i >> 7, vx = i & 127;
      tile[c][vx] = fmaf(Hin[(size_t)(cc + c) * VOXN + nb + vx], As[cc + c], Bs[cc + c]);
    }
    __syncthreads();
    #pragma unroll 4
    for (int c = 0; c < 32; ++c) {
      float t = tile[c][vox];
      const float4* wk = (const float4*)(wt + (cc + c) * 32 + q * 8);
      float4 w;
      w = wk[0]; FMA4(a0, w, t)
      w = wk[1]; FMA4(a1, w, t)
    }
  }
  RELU4(a0) RELU4(a1)
  const int ob = och + q * 8;
  #define SD_ST(A, o0) \
    H[((size_t)(ob + (o0) + 0)) * VOXN + n] = (A).x; \
    H[((size_t)(ob + (o0) + 1)) * VOXN + n] = (A).y; \
    H[((size_t)(ob + (o0) + 2)) * VOXN + n] = (A).z; \
    H[((size_t)(ob + (o0) + 3)) * VOXN + n] = (A).w;
  SD_ST(a0, 0) SD_ST(a1, 4)
  #undef SD_ST
  float ms = 0.f, mq = 0.f;
  STASH4(a0, 0) STASH4(a1, 4)
  if (lane < 8) { redS[wv][lane] = ms; redQ[wv][lane] = mq; }
  __syncthreads();
  if (tid < 32) {
    int qq = tid >> 3, ch = tid & 7;
    float s = redS[2 * qq][ch] + redS[2 * qq + 1][ch];
    float sq = redQ[2 * qq][ch] + redQ[2 * qq + 1][ch];
    atomicAdd(&stats_out[och + tid], s);
    atomicAdd(&stats_out[256 + och + tid], sq);
  }
}

// ---------------- S7: out = sigmoid(w4 @ BN(H) + b4). 512 thr = 4 quarters x 128 vox.
__global__ __launch_bounds__(512) void s7_final(
    const float* __restrict__ H, const float* __restrict__ stats_H,
    const float* __restrict__ g3d, const float* __restrict__ b3d,
    const float* __restrict__ w4t, const float* __restrict__ b4, float* __restrict__ out)
{
  __shared__ float As[256], Bs[256];
  __shared__ float tile[32][128];
  const int tid = threadIdx.x;
  const int q = tid >> 7;
  const int vox = tid & 127;
  const int nb = blockIdx.x * 128;
  const int n = nb + vox;
  if (tid < 256) {
    float m = stats_H[tid] * (1.f / VOXN);
    float vv = stats_H[256 + tid] * (1.f / VOXN) - m * m;
    float a = g3d[tid] * rsqrtf(vv + 1e-5f);
    As[tid] = a; Bs[tid] = b3d[tid] - m * a;
  }
  float acc0 = 0.f, acc1 = 0.f;
  for (int cc = 0; cc < 256; cc += 32) {
    __syncthreads();
    #pragma unroll
    for (int e = 0; e < 8; ++e) {
      int i = tid + e * 512;
      int c = i >> 7, vx = i & 127;
      tile[c][vx] = fmaf(H[(size_t)(cc + c) * VOXN + nb + vx], As[cc + c], Bs[cc + c]);
    }
    __syncthreads();
    #pragma unroll 8
    for (int c = 0; c < 32; ++c) {
      float t = tile[c][vox];
      const float2* wk = (const float2*)(w4t + (cc + c) * 8 + q * 2);
      float2 w = wk[0];
      acc0 = fmaf(w.x, t, acc0);
      acc1 = fmaf(w.y, t, acc1);
    }
  }
  const int l0 = q * 2;
  out[(size_t)(l0 + 0) * VOXN + n] = 1.f / (1.f + expf(-(acc0 + b4[l0 + 0])));
  out[(size_t)(l0 + 1) * VOXN + n] = 1.f / (1.f + expf(-(acc1 + b4[l0 + 1])));
}

extern "C" void kernel_launch(void* const* d_in, const int* in_sizes, int n_in,
                              void* d_out, int out_size, void* d_ws, size_t ws_size,
                              hipStream_t stream)
{
  const float* images  = (const float*)d_in[0];
  const float* offset1 = (const float*)d_in[1];
  const float* w1  = (const float*)d_in[2];
  const float* g1  = (const float*)d_in[3];
  const float* b1  = (const float*)d_in[4];
  const float* w2  = (const float*)d_in[5];
  const float* g2  = (const float*)d_in[6];
  const float* b2  = (const float*)d_in[7];
  const float* w3a = (const float*)d_in[8];
  const float* w3b = (const float*)d_in[9];
  const float* w3c = (const float*)d_in[10];
  const float* w3d = (const float*)d_in[11];
  const float* g3a = (const float*)d_in[12];
  const float* b3a = (const float*)d_in[13];
  const float* g3b = (const float*)d_in[14];
  const float* b3b = (const float*)d_in[15];
  const float* g3c = (const float*)d_in[16];
  const float* b3c = (const float*)d_in[17];
  const float* g3d = (const float*)d_in[18];
  const float* b3d = (const float*)d_in[19];
  const float* w4  = (const float*)d_in[20];
  const float* b4  = (const float*)d_in[21];

  float* ws  = (float*)d_ws;
  float* out = (float*)d_out;

  float* statsY = ws + OFF_STATS_Y;
  float* statsX = ws + OFF_STATS_X2P;
  float* statsH = ws + OFF_STATS_H;
  float* w1t    = ws + OFF_W1T;
  float* w2t    = ws + OFF_W2T;
  float* YH     = ws + OFF_YH;   // y, later H
  float* x2p    = ws + OFF_X2P;

  s0a_setup<<<dim3(128), dim3(256), 0, stream>>>(images, offset1, w2, w3a, w3b, w3c, w3d, w4, ws);
  s0b_rank<<<dim3(4), dim3(256), 0, stream>>>(ws);
  s0c_build<<<dim3(64), dim3(256), 0, stream>>>(offset1, w1, ws);
  s1_gather_gemm<<<dim3(256, 4), dim3(512), 0, stream>>>(
      (const float2*)(ws + OFF_PVOLP), ws + OFF_TPAR, w1t, YH, statsY);
  s2_bn_gemm<<<dim3(256), dim3(512), 0, stream>>>(YH, statsY, g1, b1, w2t, x2p, statsX);
  s3_x2_ha<<<dim3(256), dim3(512), 0, stream>>>(x2p, statsX, g2, b2, ws + OFF_W3AT, YH, statsH);
  s_dense<160><<<dim3(256), dim3(512), 0, stream>>>(YH, statsH, g3a, b3a, ws + OFF_W3BT, YH, statsH, 160);
  s_dense<192><<<dim3(256), dim3(512), 0, stream>>>(YH, statsH, g3b, b3b, ws + OFF_W3CT, YH, statsH, 192);
  s_dense<224><<<dim3(256), dim3(512), 0, stream>>>(YH, statsH, g3c, b3c, ws + OFF_W3DT, YH, statsH, 224);
  s7_final<<<dim3(256), dim3(512), 0, stream>>>(YH, statsH, g3d, b3d, ws + OFF_W4T, b4, out);
}

// Round 10
// 482.244 us; speedup vs baseline: 1.0979x; 1.0979x over previous
//
#include <hip/hip_runtime.h>
#include <math.h>

#define VOXN 32768

typedef __attribute__((ext_vector_type(8))) short bf16x8;
typedef __attribute__((ext_vector_type(4))) float f32x4;

// ---- workspace layout (float offsets) ----
constexpr int OFF_STATS_Y   = 0;        // 512
constexpr int OFF_STATS_X2P = 512;      // 256
constexpr int OFF_STATS_H   = 768;      // 512
constexpr int OFF_TPAR      = 1280;     // 1024*16 packed tap params (SORTED order)
constexpr int OFF_W1A       = 17664;    // 32768: bf16 A-frags [(g*4+mt)*8+ks][64 lanes] float4
constexpr int OFF_W2T       = 83200;    // 32768
constexpr int OFF_W3AT      = 115968;   // 4096
constexpr int OFF_W3BT      = 120064;   // 5120
constexpr int OFF_W3CT      = 125184;   // 6144
constexpr int OFF_W3DT      = 131328;   // 7168
constexpr int OFF_W4T       = 138496;   // 2048
constexpr int OFF_YH        = 140544;   // 8388608 (y, later H)
constexpr int OFF_C0A       = OFF_YH;       // 1024 ints (dead before s1 writes y)
constexpr int OFF_PERM      = OFF_YH + 1024;// 1024 ints
constexpr int OFF_X2P       = 8529152;  // 4194304 (x2pre; ALSO hosts pvolP early)
constexpr int OFF_PVOLP     = OFF_X2P;  // 941192 float2, dead before s2

#define FMA4(A, W, X) { (A).x = fmaf((W).x, (X), (A).x); (A).y = fmaf((W).y, (X), (A).y); \
                        (A).z = fmaf((W).z, (X), (A).z); (A).w = fmaf((W).w, (X), (A).w); }
#define RELU4(A) { (A).x = fmaxf((A).x, 0.f); (A).y = fmaxf((A).y, 0.f); \
                   (A).z = fmaxf((A).z, 0.f); (A).w = fmaxf((A).w, 0.f); }
#define ZERO4(A) float4 A; (A).x = 0.f; (A).y = 0.f; (A).z = 0.f; (A).w = 0.f;

#define BFLY(s, q) { s += __shfl_xor(s, 32, 64); q += __shfl_xor(q, 32, 64); \
                     s += __shfl_xor(s, 16, 64); q += __shfl_xor(q, 16, 64); \
                     s += __shfl_xor(s,  8, 64); q += __shfl_xor(q,  8, 64); \
                     s += __shfl_xor(s,  4, 64); q += __shfl_xor(q,  4, 64); \
                     s += __shfl_xor(s,  2, 64); q += __shfl_xor(q,  2, 64); \
                     s += __shfl_xor(s,  1, 64); q += __shfl_xor(q,  1, 64); }
#define STASH1(V, O) { float s_ = (V), q_ = (V) * (V); BFLY(s_, q_) \
                       if (lane == (O)) { ms = s_; mq = q_; } }
#define STASH4(A, O0) STASH1((A).x, (O0)+0) STASH1((A).y, (O0)+1) \
                      STASH1((A).z, (O0)+2) STASH1((A).w, (O0)+3)

__device__ __forceinline__ unsigned short f2bf(float f) {
  unsigned int u = __float_as_uint(f);
  u += 0x7FFFu + ((u >> 16) & 1u);     // RNE
  return (unsigned short)(u >> 16);
}

__device__ __forceinline__ float pv_at(const float* __restrict__ images, int j) {
  int x = j % 98, t = j / 98, y = t % 98, z = t / 98;
  if (x >= 33 && x < 65 && y >= 33 && y < 65 && z >= 33 && z < 65)
    return images[((z - 33) * 32 + (y - 33)) * 32 + (x - 33)];
  return 0.f;
}

__device__ __forceinline__ int tap_c0(const float* __restrict__ offset1, int k, int s) {
  float ox = fminf(fmaxf(offset1[k * 6 + s * 3 + 0] * 16.f, -1000.f), 1000.f);
  float oy = fminf(fmaxf(offset1[k * 6 + s * 3 + 1] * 16.f, -1000.f), 1000.f);
  float oz = fminf(fmaxf(offset1[k * 6 + s * 3 + 2] * 16.f, -1000.f), 1000.f);
  int sx = (int)floorf(ox), sy = (int)floorf(oy), sz = (int)floorf(oz);
  bool valid = (sx >= -33 && sx <= 32) && (sy >= -33 && sy <= 32) && (sz >= -33 && sz <= 32);
  if (!valid) { sx = sy = sz = 0; }
  return (sz + 33) * 9604 + (sy + 33) * 98 + (sx + 33);
}

// ---------------- S0a ----------------
__global__ void s0a_setup(const float* __restrict__ images, const float* __restrict__ offset1,
                          const float* __restrict__ w2,
                          const float* __restrict__ w3a, const float* __restrict__ w3b,
                          const float* __restrict__ w3c, const float* __restrict__ w3d,
                          const float* __restrict__ w4, float* __restrict__ ws)
{
  const int idx = blockIdx.x * blockDim.x + threadIdx.x;
  const int stride = gridDim.x * blockDim.x;
  for (int i = idx; i < 1280; i += stride) ws[i] = 0.f;
  float2* pp = (float2*)(ws + OFF_PVOLP);
  for (int i = idx; i < 941192; i += stride) {
    float v0 = pv_at(images, i);
    float v1 = (i + 1 < 941192) ? pv_at(images, i + 1) : 0.f;
    float2 f; f.x = v0; f.y = v1;
    pp[i] = f;
  }
  int* c0a = (int*)(ws + OFF_C0A);
  for (int k = idx; k < 1024; k += stride) c0a[k] = tap_c0(offset1, k, 0);
  for (int i = idx; i < 32768; i += stride) { int o = i & 127, c = i >> 7; ws[OFF_W2T + i] = w2[o * 256 + c]; }
  for (int i = idx; i < 4096;  i += stride) { int o = i & 31,  c = i >> 5; ws[OFF_W3AT + i] = w3a[o * 128 + c]; }
  for (int i = idx; i < 5120;  i += stride) { int o = i & 31,  c = i >> 5; ws[OFF_W3BT + i] = w3b[o * 160 + c]; }
  for (int i = idx; i < 6144;  i += stride) { int o = i & 31,  c = i >> 5; ws[OFF_W3CT + i] = w3c[o * 192 + c]; }
  for (int i = idx; i < 7168;  i += stride) { int o = i & 31,  c = i >> 5; ws[OFF_W3DT + i] = w3d[o * 224 + c]; }
  for (int i = idx; i < 2048;  i += stride) { int l = i & 7,   c = i >> 3; ws[OFF_W4T + i] = w4[l * 256 + c]; }
}

// ---------------- S0b: rank-sort taps by c0 within each group ----------------
__global__ void s0b_rank(float* __restrict__ ws)
{
  const int idx = blockIdx.x * blockDim.x + threadIdx.x;
  if (idx >= 1024) return;
  const int g = idx >> 8, k = idx & 255;
  const int* c0a = (const int*)(ws + OFF_C0A);
  int* perm = (int*)(ws + OFF_PERM);
  const int my = c0a[g * 256 + k];
  int rank = 0;
  for (int j = 0; j < 256; ++j) {
    int cj = c0a[g * 256 + j];
    rank += (cj < my) || (cj == my && j < k);
  }
  perm[g * 256 + rank] = k;
}

// ---------------- S0c: permuted tap params + bf16 A-fragment pack ----------------
__global__ void s0c_build(const float* __restrict__ offset1, const float* __restrict__ w1,
                          float* __restrict__ ws)
{
  const int idx = blockIdx.x * blockDim.x + threadIdx.x;
  const int stride = gridDim.x * blockDim.x;
  const int* perm = (const int*)(ws + OFF_PERM);
  for (int p = idx; p < 1024; p += stride) {
    const int g = p >> 8;
    const int k = g * 256 + perm[p];
    float* tp = ws + OFF_TPAR + p * 16;
    for (int s = 0; s < 2; ++s) {
      float ox = fminf(fmaxf(offset1[k * 6 + s * 3 + 0] * 16.f, -1000.f), 1000.f);
      float oy = fminf(fmaxf(offset1[k * 6 + s * 3 + 1] * 16.f, -1000.f), 1000.f);
      float oz = fminf(fmaxf(offset1[k * 6 + s * 3 + 2] * 16.f, -1000.f), 1000.f);
      float fxf = floorf(ox), fyf = floorf(oy), fzf = floorf(oz);
      float fx = ox - fxf, fy = oy - fyf, fz = oz - fzf;
      int sx = (int)fxf, sy = (int)fyf, sz = (int)fzf;
      bool valid = (sx >= -33 && sx <= 32) && (sy >= -33 && sy <= 32) && (sz >= -33 && sz <= 32);
      if (!valid) { sx = sy = sz = 0; }
      float vm = valid ? 1.f : 0.f;
      int c0 = (sz + 33) * 9604 + (sy + 33) * 98 + (sx + 33);
      float sgn = s ? -1.f : 1.f;
      float wy0 = 1.f - fy, wy1 = fy, wz0 = 1.f - fz, wz1 = fz;
      tp[s * 8 + 0] = __int_as_float(c0);
      tp[s * 8 + 1] = vm * (1.f - fx);
      tp[s * 8 + 2] = vm * fx;
      tp[s * 8 + 3] = vm * sgn * wz0 * wy0;
      tp[s * 8 + 4] = vm * sgn * wz0 * wy1;
      tp[s * 8 + 5] = vm * sgn * wz1 * wy0;
      tp[s * 8 + 6] = vm * sgn * wz1 * wy1;
      tp[s * 8 + 7] = 0.f;
    }
  }
  // A-frag pack: i indexes dwords (2 bf16). lane l: row = mt*16+(l&15),
  // k = ks*32 + (l>>4)*8 + j  (same k-slot mapping as the B LDS layout -> any
  // HW permutation of k-slots cancels in the dot product).
  for (int i = idx; i < 32768; i += stride) {
    int jp = i & 3;
    int l  = (i >> 2) & 63;
    int ks = (i >> 8) & 7;
    int mt = (i >> 11) & 3;
    int g  = i >> 13;
    int row = mt * 16 + (l & 15);
    int kbase = g * 256 + ks * 32 + (l >> 4) * 8 + jp * 2;
    int ka = perm[kbase], kb = perm[kbase + 1];
    unsigned short b0 = f2bf(w1[g * 16384 + row * 256 + ka]);
    unsigned short b1 = f2bf(w1[g * 16384 + row * 256 + kb]);
    ws[OFF_W1A + i] = __uint_as_float((unsigned int)b0 | ((unsigned int)b1 << 16));
  }
}

// ---------------- S1: fused gather + MFMA grouped GEMM ----------------
// 256 thr = 4 waves; 128 voxels (N), 64 outputs (M), K=256 in 4 chunks of 64.
// Gather -> bf16 x-tile in LDS [128 v][72 k-pad]; each wave = one 16-row m-tile,
// 8 n-tiles x 2 k-steps of mfma_f32_16x16x32_bf16 per chunk.
__global__ __launch_bounds__(256, 4) void s1_gather_gemm(
    const float2* __restrict__ pvolP, const float* __restrict__ tparP,
    const float4* __restrict__ apack, float* __restrict__ y, float* __restrict__ stats_y)
{
  __shared__ unsigned short xt[128 * 72];   // 18432 B, row stride 144 B (16B aligned)
  const int tid = threadIdx.x;
  const int lane = tid & 63;
  const int wv = tid >> 6;          // m-tile 0..3
  const int g = blockIdx.y;
  const int v0 = blockIdx.x * 128;
  const int n = tid & 127;
  const int khalf = tid >> 7;       // 0/1: k-half of chunk
  const int v = v0 + n;
  const int vbase = (v >> 10) * 9604 + ((v >> 5) & 31) * 98 + (v & 31);
  const float4* tq_base = (const float4*)(tparP + g * 4096);

  f32x4 acc[8];
  #pragma unroll
  for (int i = 0; i < 8; ++i) acc[i] = (f32x4){0.f, 0.f, 0.f, 0.f};

  for (int ch = 0; ch < 4; ++ch) {
    const int kb = ch * 64 + khalf * 32;
    __syncthreads();                       // prev MFMA reads done before overwrite
    #pragma unroll 2
    for (int i2 = 0; i2 < 32; i2 += 2) {
      float xv0, xv1;
      {
        const int kt = kb + i2;
        float4 t0 = tq_base[kt*4+0], t1 = tq_base[kt*4+1], t2 = tq_base[kt*4+2], t3 = tq_base[kt*4+3];
        const float2* p = pvolP + (vbase + __float_as_int(t0.x));
        float2 r0 = p[0], r1 = p[98], r2 = p[9604], r3 = p[9702];
        float xval = (r0.x*t0.y + r0.y*t0.z)*t0.w + (r1.x*t0.y + r1.y*t0.z)*t1.x
                   + (r2.x*t0.y + r2.y*t0.z)*t1.y + (r3.x*t0.y + r3.y*t0.z)*t1.z;
        const float2* q = pvolP + (vbase + __float_as_int(t2.x));
        float2 s0 = q[0], s1 = q[98], s2 = q[9604], s3 = q[9702];
        xval += (s0.x*t2.y + s0.y*t2.z)*t2.w + (s1.x*t2.y + s1.y*t2.z)*t3.x
              + (s2.x*t2.y + s2.y*t2.z)*t3.y + (s3.x*t2.y + s3.y*t2.z)*t3.z;
        xv0 = xval;
      }
      {
        const int kt = kb + i2 + 1;
        float4 t0 = tq_base[kt*4+0], t1 = tq_base[kt*4+1], t2 = tq_base[kt*4+2], t3 = tq_base[kt*4+3];
        const float2* p = pvolP + (vbase + __float_as_int(t0.x));
        float2 r0 = p[0], r1 = p[98], r2 = p[9604], r3 = p[9702];
        float xval = (r0.x*t0.y + r0.y*t0.z)*t0.w + (r1.x*t0.y + r1.y*t0.z)*t1.x
                   + (r2.x*t0.y + r2.y*t0.z)*t1.y + (r3.x*t0.y + r3.y*t0.z)*t1.z;
        const float2* q = pvolP + (vbase + __float_as_int(t2.x));
        float2 s0 = q[0], s1 = q[98], s2 = q[9604], s3 = q[9702];
        xval += (s0.x*t2.y + s0.y*t2.z)*t2.w + (s1.x*t2.y + s1.y*t2.z)*t3.x
              + (s2.x*t2.y + s2.y*t2.z)*t3.y + (s3.x*t2.y + s3.y*t2.z)*t3.z;
        xv1 = xval;
      }
      unsigned int pk = (unsigned int)f2bf(xv0) | ((unsigned int)f2bf(xv1) << 16);
      *(unsigned int*)&xt[n * 72 + khalf * 32 + i2] = pk;
    }
    __syncthreads();
    #pragma unroll
    for (int s = 0; s < 2; ++s) {
      float4 araw = apack[(((g * 4 + wv) * 8) + ch * 2 + s) * 64 + lane];
      bf16x8 a = *reinterpret_cast<bf16x8*>(&araw);
      #pragma unroll
      for (int nt = 0; nt < 8; ++nt) {
        const unsigned short* bp = &xt[(nt * 16 + (lane & 15)) * 72 + s * 32 + (lane >> 4) * 8];
        float4 braw = *(const float4*)bp;
        bf16x8 b = *reinterpret_cast<bf16x8*>(&braw);
        acc[nt] = __builtin_amdgcn_mfma_f32_16x16x32_bf16(a, b, acc[nt], 0, 0, 0);
      }
    }
  }
  // ---- store y + stats. C/D layout (m89): col = lane&15, row = (lane>>4)*4 + r ----
  const int obase = g << 6;
  float srow0 = 0.f, srow1 = 0.f, srow2 = 0.f, srow3 = 0.f;
  float qrow0 = 0.f, qrow1 = 0.f, qrow2 = 0.f, qrow3 = 0.f;
  #pragma unroll
  for (int nt = 0; nt < 8; ++nt) {
    const int col = v0 + nt * 16 + (lane & 15);
    const int rbase = obase + wv * 16 + (lane >> 4) * 4;
    float e0 = acc[nt][0], e1 = acc[nt][1], e2 = acc[nt][2], e3 = acc[nt][3];
    y[(size_t)(rbase + 0) * VOXN + col] = e0;
    y[(size_t)(rbase + 1) * VOXN + col] = e1;
    y[(size_t)(rbase + 2) * VOXN + col] = e2;
    y[(size_t)(rbase + 3) * VOXN + col] = e3;
    srow0 += e0; qrow0 += e0 * e0;
    srow1 += e1; qrow1 += e1 * e1;
    srow2 += e2; qrow2 += e2 * e2;
    srow3 += e3; qrow3 += e3 * e3;
  }
  #define ROWRED(S, Q, R) { \
    float s_ = S, q_ = Q; \
    s_ += __shfl_xor(s_, 1, 64); q_ += __shfl_xor(q_, 1, 64); \
    s_ += __shfl_xor(s_, 2, 64); q_ += __shfl_xor(q_, 2, 64); \
    s_ += __shfl_xor(s_, 4, 64); q_ += __shfl_xor(q_, 4, 64); \
    s_ += __shfl_xor(s_, 8, 64); q_ += __shfl_xor(q_, 8, 64); \
    if ((lane & 15) == 0) { \
      int row = obase + wv * 16 + (lane >> 4) * 4 + (R); \
      atomicAdd(&stats_y[row], s_); atomicAdd(&stats_y[256 + row], q_); } }
  ROWRED(srow0, qrow0, 0) ROWRED(srow1, qrow1, 1)
  ROWRED(srow2, qrow2, 2) ROWRED(srow3, qrow3, 3)
  #undef ROWRED
}

// ---------------- S2: x1 = relu(BN(y)); x2pre = w2 @ x1 (32 outputs/block) ----------------
__global__ __launch_bounds__(256) void s2_bn_gemm(
    const float* __restrict__ y, const float* __restrict__ stats_y,
    const float* __restrict__ g1, const float* __restrict__ b1,
    const float* __restrict__ w2t, float* __restrict__ x2p, float* __restrict__ stats_x2p)
{
  __shared__ float As[256], Bs[256];
  __shared__ float redS[4][32], redQ[4][32];
  const int tid = threadIdx.x;
  const int lane = tid & 63;
  const int wv = tid >> 6;
  {
    float m = stats_y[tid] * (1.f / VOXN);
    float vv = stats_y[256 + tid] * (1.f / VOXN) - m * m;
    float a = g1[tid] * rsqrtf(vv + 1e-5f);
    As[tid] = a; Bs[tid] = b1[tid] - m * a;
  }
  __syncthreads();
  const int q = blockIdx.y;
  const int n = blockIdx.x * 256 + tid;
  ZERO4(a0) ZERO4(a1) ZERO4(a2) ZERO4(a3) ZERO4(a4) ZERO4(a5) ZERO4(a6) ZERO4(a7)
  #pragma unroll 4
  for (int c = 0; c < 256; ++c) {
    float t = fmaxf(fmaf(y[(size_t)c * VOXN + n], As[c], Bs[c]), 0.f);
    const float4* wk = (const float4*)(w2t + c * 128 + q * 32);
    float4 w;
    w = wk[0]; FMA4(a0, w, t)
    w = wk[1]; FMA4(a1, w, t)
    w = wk[2]; FMA4(a2, w, t)
    w = wk[3]; FMA4(a3, w, t)
    w = wk[4]; FMA4(a4, w, t)
    w = wk[5]; FMA4(a5, w, t)
    w = wk[6]; FMA4(a6, w, t)
    w = wk[7]; FMA4(a7, w, t)
  }
  const int ob = q * 32;
  #define S2_ST(A, o0) \
    x2p[((size_t)(ob + (o0) + 0)) * VOXN + n] = (A).x; \
    x2p[((size_t)(ob + (o0) + 1)) * VOXN + n] = (A).y; \
    x2p[((size_t)(ob + (o0) + 2)) * VOXN + n] = (A).z; \
    x2p[((size_t)(ob + (o0) + 3)) * VOXN + n] = (A).w;
  S2_ST(a0, 0) S2_ST(a1, 4) S2_ST(a2, 8) S2_ST(a3, 12)
  S2_ST(a4, 16) S2_ST(a5, 20) S2_ST(a6, 24) S2_ST(a7, 28)
  #undef S2_ST
  float ms = 0.f, mq = 0.f;
  STASH4(a0, 0) STASH4(a1, 4) STASH4(a2, 8) STASH4(a3, 12)
  STASH4(a4, 16) STASH4(a5, 20) STASH4(a6, 24) STASH4(a7, 28)
  if (lane < 32) { redS[wv][lane] = ms; redQ[wv][lane] = mq; }
  __syncthreads();
  if (tid < 32) {
    float s = redS[0][tid] + redS[1][tid] + redS[2][tid] + redS[3][tid];
    float qq = redQ[0][tid] + redQ[1][tid] + redQ[2][tid] + redQ[3][tid];
    atomicAdd(&stats_x2p[ob + tid], s);
    atomicAdd(&stats_x2p[128 + ob + tid], qq);
  }
}

// ---------------- S3 ----------------
__global__ __launch_bounds__(256) void s3_x2_ha(
    const float* __restrict__ x2p, const float* __restrict__ stats_x2p,
    const float* __restrict__ g2, const float* __restrict__ b2,
    const float* __restrict__ w3at, float* __restrict__ H, float* __restrict__ stats_H)
{
  __shared__ float As[128], Bs[128];
  __shared__ float redS[4][8], redQ[4][8];
  const int tid = threadIdx.x;
  const int lane = tid & 63;
  const int wv = tid >> 6;
  if (tid < 128) {
    float m = stats_x2p[tid] * (1.f / VOXN);
    float vv = stats_x2p[128 + tid] * (1.f / VOXN) - m * m;
    float a = g2[tid] * rsqrtf(vv + 1e-5f);
    As[tid] = a; Bs[tid] = b2[tid] - m * a;
    if (blockIdx.x == 0 && blockIdx.y == 0) {
      float mean = b2[tid];
      float var = a * a * vv;
      stats_H[tid] = mean * (float)VOXN;
      stats_H[256 + tid] = (var + mean * mean) * (float)VOXN;
    }
  }
  __syncthreads();
  const int qh = blockIdx.y;
  const int n = blockIdx.x * 256 + tid;
  ZERO4(a0) ZERO4(a1)
  #pragma unroll 8
  for (int c = 0; c < 128; ++c) {
    float x2v = fmaf(x2p[(size_t)c * VOXN + n], As[c], Bs[c]);
    if (qh == 0) H[(size_t)c * VOXN + n] = x2v;
    const float4* wk = (const float4*)(w3at + c * 32 + qh * 8);
    float4 w;
    w = wk[0]; FMA4(a0, w, x2v)
    w = wk[1]; FMA4(a1, w, x2v)
  }
  RELU4(a0) RELU4(a1)
  const int ob = 128 + qh * 8;
  #define S3_ST(A, o0) \
    H[((size_t)(ob + (o0) + 0)) * VOXN + n] = (A).x; \
    H[((size_t)(ob + (o0) + 1)) * VOXN + n] = (A).y; \
    H[((size_t)(ob + (o0) + 2)) * VOXN + n] = (A).z; \
    H[((size_t)(ob + (o0) + 3)) * VOXN + n] = (A).w;
  S3_ST(a0, 0) S3_ST(a1, 4)
  #undef S3_ST
  float ms = 0.f, mq = 0.f;
  STASH4(a0, 0) STASH4(a1, 4)
  if (lane < 8) { redS[wv][lane] = ms; redQ[wv][lane] = mq; }
  __syncthreads();
  if (tid < 8) {
    float s = redS[0][tid] + redS[1][tid] + redS[2][tid] + redS[3][tid];
    float qq = redQ[0][tid] + redQ[1][tid] + redQ[2][tid] + redQ[3][tid];
    atomicAdd(&stats_H[ob + tid], s);
    atomicAdd(&stats_H[256 + ob + tid], qq);
  }
}

// ---------------- S4/5/6 ----------------
template<int CIN>
__global__ __launch_bounds__(256) void s_dense(
    const float* __restrict__ Hin, const float* __restrict__ stats_H,
    const float* __restrict__ g, const float* __restrict__ b,
    const float* __restrict__ wt, float* __restrict__ H, float* __restrict__ stats_out, int och)
{
  __shared__ float As[CIN], Bs[CIN];
  __shared__ float redS[4][8], redQ[4][8];
  const int tid = threadIdx.x;
  const int lane = tid & 63;
  const int wv = tid >> 6;
  if (tid < CIN) {
    float m = stats_H[tid] * (1.f / VOXN);
    float vv = stats_H[256 + tid] * (1.f / VOXN) - m * m;
    float a = g[tid] * rsqrtf(vv + 1e-5f);
    As[tid] = a; Bs[tid] = b[tid] - m * a;
  }
  __syncthreads();
  const int osub = blockIdx.y * 8;
  const int n = blockIdx.x * 256 + tid;
  ZERO4(a0) ZERO4(a1)
  #pragma unroll 8
  for (int c = 0; c < CIN; ++c) {
    float t = fmaf(Hin[(size_t)c * VOXN + n], As[c], Bs[c]);
    const float4* wk = (const float4*)(wt + c * 32 + osub);
    float4 w;
    w = wk[0]; FMA4(a0, w, t)
    w = wk[1]; FMA4(a1, w, t)
  }
  RELU4(a0) RELU4(a1)
  const int ob = och + osub;
  #define SD_ST(A, o0) \
    H[((size_t)(ob + (o0) + 0)) * VOXN + n] = (A).x; \
    H[((size_t)(ob + (o0) + 1)) * VOXN + n] = (A).y; \
    H[((size_t)(ob + (o0) + 2)) * VOXN + n] = (A).z; \
    H[((size_t)(ob + (o0) + 3)) * VOXN + n] = (A).w;
  SD_ST(a0, 0) SD_ST(a1, 4)
  #undef SD_ST
  float ms = 0.f, mq = 0.f;
  STASH4(a0, 0) STASH4(a1, 4)
  if (lane < 8) { redS[wv][lane] = ms; redQ[wv][lane] = mq; }
  __syncthreads();
  if (tid < 8) {
    float s = redS[0][tid] + redS[1][tid] + redS[2][tid] + redS[3][tid];
    float qq = redQ[0][tid] + redQ[1][tid] + redQ[2][tid] + redQ[3][tid];
    atomicAdd(&stats_out[ob + tid], s);
    atomicAdd(&stats_out[256 + ob + tid], qq);
  }
}

// ---------------- S7 ----------------
__global__ __launch_bounds__(256) void s7_final(
    const float* __restrict__ H, const float* __restrict__ stats_H,
    const float* __restrict__ g3d, const float* __restrict__ b3d,
    const float* __restrict__ w4t, const float* __restrict__ b4, float* __restrict__ out)
{
  __shared__ float As[256], Bs[256];
  const int tid = threadIdx.x;
  {
    float m = stats_H[tid] * (1.f / VOXN);
    float vv = stats_H[256 + tid] * (1.f / VOXN) - m * m;
    float a = g3d[tid] * rsqrtf(vv + 1e-5f);
    As[tid] = a; Bs[tid] = b3d[tid] - m * a;
  }
  __syncthreads();
  const int n = blockIdx.x * 256 + tid;
  ZERO4(a0) ZERO4(a1)
  #pragma unroll 8
  for (int c = 0; c < 256; ++c) {
    float t = fmaf(H[(size_t)c * VOXN + n], As[c], Bs[c]);
    const float4* wk = (const float4*)(w4t + c * 8);
    float4 w;
    w = wk[0]; FMA4(a0, w, t)
    w = wk[1]; FMA4(a1, w, t)
  }
  out[(size_t)0 * VOXN + n] = 1.f / (1.f + expf(-(a0.x + b4[0])));
  out[(size_t)1 * VOXN + n] = 1.f / (1.f + expf(-(a0.y + b4[1])));
  out[(size_t)2 * VOXN + n] = 1.f / (1.f + expf(-(a0.z + b4[2])));
  out[(size_t)3 * VOXN + n] = 1.f / (1.f + expf(-(a0.w + b4[3])));
  out[(size_t)4 * VOXN + n] = 1.f / (1.f + expf(-(a1.x + b4[4])));
  out[(size_t)5 * VOXN + n] = 1.f / (1.f + expf(-(a1.y + b4[5])));
  out[(size_t)6 * VOXN + n] = 1.f / (1.f + expf(-(a1.z + b4[6])));
  out[(size_t)7 * VOXN + n] = 1.f / (1.f + expf(-(a1.w + b4[7])));
}

extern "C" void kernel_launch(void* const* d_in, const int* in_sizes, int n_in,
                              void* d_out, int out_size, void* d_ws, size_t ws_size,
                              hipStream_t stream)
{
  const float* images  = (const float*)d_in[0];
  const float* offset1 = (const float*)d_in[1];
  const float* w1  = (const float*)d_in[2];
  const float* g1  = (const float*)d_in[3];
  const float* b1  = (const float*)d_in[4];
  const float* w2  = (const float*)d_in[5];
  const float* g2  = (const float*)d_in[6];
  const float* b2  = (const float*)d_in[7];
  const float* w3a = (const float*)d_in[8];
  const float* w3b = (const float*)d_in[9];
  const float* w3c = (const float*)d_in[10];
  const float* w3d = (const float*)d_in[11];
  const float* g3a = (const float*)d_in[12];
  const float* b3a = (const float*)d_in[13];
  const float* g3b = (const float*)d_in[14];
  const float* b3b = (const float*)d_in[15];
  const float* g3c = (const float*)d_in[16];
  const float* b3c = (const float*)d_in[17];
  const float* g3d = (const float*)d_in[18];
  const float* b3d = (const float*)d_in[19];
  const float* w4  = (const float*)d_in[20];
  const float* b4  = (const float*)d_in[21];

  float* ws  = (float*)d_ws;
  float* out = (float*)d_out;

  float* statsY = ws + OFF_STATS_Y;
  float* statsX = ws + OFF_STATS_X2P;
  float* statsH = ws + OFF_STATS_H;
  float* w2t    = ws + OFF_W2T;
  float* YH     = ws + OFF_YH;   // y, later H
  float* x2p    = ws + OFF_X2P;

  s0a_setup<<<dim3(128), dim3(256), 0, stream>>>(images, offset1, w2, w3a, w3b, w3c, w3d, w4, ws);
  s0b_rank<<<dim3(4), dim3(256), 0, stream>>>(ws);
  s0c_build<<<dim3(64), dim3(256), 0, stream>>>(offset1, w1, ws);
  s1_gather_gemm<<<dim3(256, 4), dim3(256), 0, stream>>>(
      (const float2*)(ws + OFF_PVOLP), ws + OFF_TPAR,
      (const float4*)(ws + OFF_W1A), YH, statsY);
  s2_bn_gemm<<<dim3(128, 4), dim3(256), 0, stream>>>(YH, statsY, g1, b1, w2t, x2p, statsX);
  s3_x2_ha<<<dim3(128, 4), dim3(256), 0, stream>>>(x2p, statsX, g2, b2, ws + OFF_W3AT, YH, statsH);
  s_dense<160><<<dim3(128, 4), dim3(256), 0, stream>>>(YH, statsH, g3a, b3a, ws + OFF_W3BT, YH, statsH, 160);
  s_dense<192><<<dim3(128, 4), dim3(256), 0, stream>>>(YH, statsH, g3b, b3b, ws + OFF_W3CT, YH, statsH, 192);
  s_dense<224><<<dim3(128, 4), dim3(256), 0, stream>>>(YH, statsH, g3c, b3c, ws + OFF_W3DT, YH, statsH, 224);
  s7_final<<<dim3(128), dim3(256), 0, stream>>>(YH, statsH, g3d, b3d, ws + OFF_W4T, b4, out);
}